// Round 5
// baseline (388.286 us; speedup 1.0000x reference)
//
#include <hip/hip_runtime.h>

#define N_NODES 100000

// ---- bf16 helpers (manual, RNE) -------------------------------------------
__device__ __forceinline__ unsigned short f2bf_rn(float f) {
    unsigned int b = __float_as_uint(f);
    b += 0x7fffu + ((b >> 16) & 1u);
    return (unsigned short)(b >> 16);
}
__device__ __forceinline__ float bf_lo(unsigned int u) { return __uint_as_float(u << 16); }
__device__ __forceinline__ float bf_hi(unsigned int u) { return __uint_as_float(u & 0xffff0000u); }

// nontemporal 8B load of an int2 (single dwordx2, nt-hint keeps L2 for gathers)
__device__ __forceinline__ int2 ld_nt_i2(const int2* p) {
    union { long long l; int2 v; } u;
    u.l = __builtin_nontemporal_load((const long long*)p);
    return u.v;
}

// ============================ degree + dinv ================================

__global__ __launch_bounds__(256) void hist_kernel(const int* __restrict__ dst, int E,
                                                   unsigned int* __restrict__ deg) {
    int i = blockIdx.x * 256 + threadIdx.x;
    if (i < E) atomicAdd(&deg[dst[i]], 1u);
}

__global__ __launch_bounds__(256) void dinv_kernel(const unsigned int* __restrict__ deg,
                                                   float* __restrict__ dinv, int n) {
    int i = blockIdx.x * 256 + threadIdx.x;
    if (i < n) dinv[i] = rsqrtf((float)deg[i] + 1.0f);
}

// ======================= row_start = exclusive scan(deg) ===================

__global__ __launch_bounds__(256) void scanA_kernel(const unsigned int* __restrict__ deg,
                                                    int n, unsigned int* __restrict__ totals) {
    __shared__ unsigned int s[256];
    int t = threadIdx.x;
    int base = blockIdx.x * 1024 + t * 4;
    unsigned int sum = 0;
#pragma unroll
    for (int k = 0; k < 4; ++k) { int i = base + k; if (i < n) sum += deg[i]; }
    s[t] = sum; __syncthreads();
    for (int off = 128; off > 0; off >>= 1) {
        if (t < off) s[t] += s[t + off];
        __syncthreads();
    }
    if (t == 0) totals[blockIdx.x] = s[0];
}

__global__ __launch_bounds__(128) void scanB_kernel(const unsigned int* __restrict__ totals,
                                                    int nblk, unsigned int* __restrict__ offsets,
                                                    int* __restrict__ row_start, int n, int E) {
    __shared__ unsigned int s[128];
    int t = threadIdx.x;
    unsigned int v = (t < nblk) ? totals[t] : 0u;
    s[t] = v; __syncthreads();
    for (int off = 1; off < 128; off <<= 1) {
        unsigned int x = s[t];
        unsigned int y = (t >= off) ? s[t - off] : 0u;
        __syncthreads();
        s[t] = x + y;
        __syncthreads();
    }
    if (t < nblk) offsets[t] = s[t] - v;
    if (t == 0) row_start[n] = E;
}

// scanC also emits bucket_cursor[b] = row_start[b*512] (bin bucket bases)
__global__ __launch_bounds__(256) void scanC_kernel(const unsigned int* __restrict__ deg,
                                                    const unsigned int* __restrict__ offsets,
                                                    int n, int* __restrict__ row_start,
                                                    unsigned int* __restrict__ bucket_cursor) {
    __shared__ unsigned int s[256];
    int t = threadIdx.x;
    int base = blockIdx.x * 1024 + t * 4;
    unsigned int v[4];
    unsigned int sum = 0;
#pragma unroll
    for (int k = 0; k < 4; ++k) { int i = base + k; v[k] = (i < n) ? deg[i] : 0u; sum += v[k]; }
    s[t] = sum; __syncthreads();
    for (int off = 1; off < 256; off <<= 1) {
        unsigned int x = s[t];
        unsigned int y = (t >= off) ? s[t - off] : 0u;
        __syncthreads();
        s[t] = x + y;
        __syncthreads();
    }
    unsigned int excl = s[t] - sum + offsets[blockIdx.x];
#pragma unroll
    for (int k = 0; k < 4; ++k) {
        int i = base + k;
        if (i < n) {
            row_start[i] = (int)excl;
            if ((i & 511) == 0) bucket_cursor[i >> 9] = excl;
        }
        excl += v[k];
    }
}

// =================== bin: group edges by 512-node bucket ===================
// Block = 4096 edges. LDS count per bucket -> one global atomic per
// (block,bucket) reserves a contiguous run -> packed 4B entries written via
// LDS cursors. Entry: src (17b) | dst&511 (9b)<<17.
__global__ __launch_bounds__(256) void bin_kernel(const int* __restrict__ ei, int E,
                                                  unsigned int* __restrict__ bucket_cursor,
                                                  unsigned int* __restrict__ binned) {
    __shared__ unsigned int cnt[256];
    __shared__ unsigned int cur[256];
    int t = threadIdx.x;
    cnt[t] = 0;
    __syncthreads();
    int base = blockIdx.x * 4096;
    unsigned int pk[16];
    unsigned int bk[16];
#pragma unroll
    for (int k = 0; k < 16; ++k) {
        int e = base + k * 256 + t;
        if (e < E) {
            int s = __builtin_nontemporal_load(&ei[e]);
            int d = __builtin_nontemporal_load(&ei[E + e]);
            unsigned int b = (unsigned int)d >> 9;
            pk[k] = (unsigned int)s | (((unsigned int)d & 511u) << 17);
            bk[k] = b;
            atomicAdd(&cnt[b], 1u);
        } else {
            bk[k] = 0xFFFFFFFFu;
        }
    }
    __syncthreads();
    if (cnt[t] > 0) cur[t] = atomicAdd(&bucket_cursor[t], cnt[t]);
    __syncthreads();
#pragma unroll
    for (int k = 0; k < 16; ++k) {
        if (bk[k] != 0xFFFFFFFFu) {
            unsigned int pos = atomicAdd(&cur[bk[k]], 1u);
            binned[pos] = pk[k];
        }
    }
}

// ============ place: one block per bucket -> final CSR (src, norm) =========
__global__ __launch_bounds__(1024) void place_kernel(const unsigned int* __restrict__ binned,
                                                     const int* __restrict__ row_start,
                                                     const float* __restrict__ dinv,
                                                     int2* __restrict__ csr, int N) {
    __shared__ int cur[512];
    __shared__ float dv[512];
    int t = threadIdx.x;
    int node0 = blockIdx.x << 9;
    if (t < 512) {
        int idx = node0 + t;
        int g = idx < N ? idx : N;
        cur[t] = row_start[g];
        dv[t] = dinv[idx < N ? idx : (N - 1)];
    }
    int endn = node0 + 512; if (endn > N) endn = N;
    int beg = row_start[node0];
    int end = row_start[endn];
    __syncthreads();
    for (int i = beg + t; i < end; i += 1024) {
        unsigned int u = __builtin_nontemporal_load(&binned[i]);
        int s = (int)(u & 0x1FFFFu);
        int doff = (int)(u >> 17);
        int slot = atomicAdd(&cur[doff], 1);
        int2 ent; ent.x = s; ent.y = __float_as_int(dinv[s] * dv[doff]);
        csr[slot] = ent;
    }
}

// ==================== GEMM1: h1[N,64](bf16) = x @ W1 =======================
__global__ __launch_bounds__(256) void gemm1_kernel(
    const float* __restrict__ x, const float* __restrict__ W,
    unsigned short* __restrict__ h1b, int N) {
    __shared__ float Ws[128 * 64];
    __shared__ float xs[16 * 128];
    int tid = threadIdx.x;
    const float4* W4 = (const float4*)W;
    float4* Ws4 = (float4*)Ws;
#pragma unroll
    for (int i = 0; i < 8; ++i) Ws4[tid + 256 * i] = W4[tid + 256 * i];
    int row0 = blockIdx.x * 16;
    const float4* x4 = (const float4*)(x + (size_t)row0 * 128);
    float4* xs4 = (float4*)xs;
#pragma unroll
    for (int i = 0; i < 2; ++i) xs4[tid + 256 * i] = x4[tid + 256 * i];
    __syncthreads();
    int j = tid & 63;
    int rg = tid >> 6;
    float acc0 = 0.f, acc1 = 0.f, acc2 = 0.f, acc3 = 0.f;
#pragma unroll 8
    for (int k = 0; k < 128; ++k) {
        float w = Ws[k * 64 + j];
        acc0 += xs[(rg + 0) * 128 + k] * w;
        acc1 += xs[(rg + 4) * 128 + k] * w;
        acc2 += xs[(rg + 8) * 128 + k] * w;
        acc3 += xs[(rg + 12) * 128 + k] * w;
    }
    float accs[4] = {acc0, acc1, acc2, acc3};
#pragma unroll
    for (int i = 0; i < 4; ++i) {
        int r = row0 + rg + i * 4;
        h1b[(size_t)r * 64 + j] = f2bf_rn(accs[i]);
    }
}

// ============ Aggregation 1 (+bias+relu) fused with GEMM2 ==================
// Full 64-lane wave per dst node: lane = (e2 = lane>>5, jp = lane&31).
// Each 32-lane half walks alternate edges (stride 2), unroll-2 -> 4 gather
// chains in flight per node. Cross-half shfl_xor(32) reduces; self-loop+bias
// added post-reduction. GEMM2: halves split the k-range, shfl_xor combine.
__global__ __launch_bounds__(256) void agg1_kernel(
    const unsigned int* __restrict__ h1u,   // [N,32] bf16-pairs
    const int2* __restrict__ csr,
    const int* __restrict__ row_start, const float* __restrict__ dinv,
    const float* __restrict__ b1, const float* __restrict__ W2,
    unsigned short* __restrict__ h2b, int N) {
    __shared__ float W2s[64 * 32];
    __shared__ float hr[4][64];
    int tid = threadIdx.x;
    const float4* W24 = (const float4*)W2;
    float4* W2s4 = (float4*)W2s;
#pragma unroll
    for (int i = 0; i < 2; ++i) W2s4[tid + 256 * i] = W24[tid + 256 * i];
    __syncthreads();
    int wid = tid >> 6;
    int lane = tid & 63;
    int e2 = lane >> 5;          // edge-parity half
    int jp = lane & 31;          // feature pair
    int d = blockIdx.x * 4 + wid;
    if (d >= N) return;          // no barriers after this point
    float di = dinv[d];
    float2 bias = ((const float2*)b1)[jp];
    unsigned int su = h1u[(size_t)d * 32 + jp];
    int beg = row_start[d], end = row_start[d + 1];
    float a0 = 0.f, a1 = 0.f;
    int e = beg + e2;
    for (; e + 2 < end; e += 4) {
        int2 c0 = ld_nt_i2(&csr[e]);
        int2 c1 = ld_nt_i2(&csr[e + 2]);
        unsigned int u0 = h1u[(size_t)c0.x * 32 + jp];
        unsigned int u1 = h1u[(size_t)c1.x * 32 + jp];
        float n0 = __int_as_float(c0.y), n1 = __int_as_float(c1.y);
        a0 += bf_lo(u0) * n0; a1 += bf_hi(u0) * n0;
        a0 += bf_lo(u1) * n1; a1 += bf_hi(u1) * n1;
    }
    if (e < end) {
        int2 c0 = ld_nt_i2(&csr[e]);
        unsigned int u0 = h1u[(size_t)c0.x * 32 + jp];
        float n0 = __int_as_float(c0.y);
        a0 += bf_lo(u0) * n0; a1 += bf_hi(u0) * n0;
    }
    a0 += __shfl_xor(a0, 32);
    a1 += __shfl_xor(a1, 32);
    float h0 = a0 + bf_lo(su) * di * di + bias.x; h0 = fmaxf(h0, 0.f);
    float h1v = a1 + bf_hi(su) * di * di + bias.y; h1v = fmaxf(h1v, 0.f);
    if (e2 == 0) {
        hr[wid][2 * jp] = h0;
        hr[wid][2 * jp + 1] = h1v;
    }
    // GEMM2: halves split k-range; intra-wave LDS RAW ordered by lgkmcnt
    const float* hrw = hr[wid];
    int k0 = e2 * 32;
    float p = 0.f;
#pragma unroll 8
    for (int k = 0; k < 32; ++k)
        p += hrw[k0 + k] * W2s[(k0 + k) * 32 + jp];
    p += __shfl_xor(p, 32);
    if (e2 == 0) h2b[(size_t)d * 32 + jp] = f2bf_rn(p);
}

// ===================== Aggregation 2 -> out (final layer) ==================
// 32 lanes per node: (e2 = parity, jp = pair of 16). 4 gather chains/node.
__global__ __launch_bounds__(256) void agg2_kernel(
    const unsigned int* __restrict__ h2u,   // [N,16] bf16-pairs
    const int2* __restrict__ csr,
    const int* __restrict__ row_start, const float* __restrict__ dinv,
    const float* __restrict__ b2, float* __restrict__ out, int N) {
    int t = blockIdx.x * 256 + threadIdx.x;
    int d = t >> 5;
    int lane = t & 31;
    int e2 = lane >> 4;
    int jp = lane & 15;
    if (d >= N) return;
    float di = dinv[d];
    float2 bias = ((const float2*)b2)[jp];
    unsigned int su = h2u[(size_t)d * 16 + jp];
    int beg = row_start[d], end = row_start[d + 1];
    float a0 = 0.f, a1 = 0.f;
    int e = beg + e2;
    for (; e + 2 < end; e += 4) {
        int2 c0 = ld_nt_i2(&csr[e]);
        int2 c1 = ld_nt_i2(&csr[e + 2]);
        unsigned int u0 = h2u[(size_t)c0.x * 16 + jp];
        unsigned int u1 = h2u[(size_t)c1.x * 16 + jp];
        float n0 = __int_as_float(c0.y), n1 = __int_as_float(c1.y);
        a0 += bf_lo(u0) * n0; a1 += bf_hi(u0) * n0;
        a0 += bf_lo(u1) * n1; a1 += bf_hi(u1) * n1;
    }
    if (e < end) {
        int2 c0 = ld_nt_i2(&csr[e]);
        unsigned int u0 = h2u[(size_t)c0.x * 16 + jp];
        float n0 = __int_as_float(c0.y);
        a0 += bf_lo(u0) * n0; a1 += bf_hi(u0) * n0;
    }
    a0 += __shfl_xor(a0, 16);
    a1 += __shfl_xor(a1, 16);
    if (e2 == 0) {
        float2 r;
        r.x = a0 + bf_lo(su) * di * di + bias.x;
        r.y = a1 + bf_hi(su) * di * di + bias.y;
        ((float2*)(out + (size_t)d * 32))[jp] = r;
    }
}

extern "C" void kernel_launch(void* const* d_in, const int* in_sizes, int n_in,
                              void* d_out, int out_size, void* d_ws, size_t ws_size,
                              hipStream_t stream) {
    const float* x  = (const float*)d_in[0];
    const int*   ei = (const int*)d_in[1];
    const float* W1 = (const float*)d_in[2];
    const float* b1 = (const float*)d_in[3];
    const float* W2 = (const float*)d_in[4];
    const float* b2 = (const float*)d_in[5];
    float* out = (float*)d_out;

    const int N = N_NODES;
    const int E = in_sizes[1] / 2;
    const int NBLK = (N + 1023) / 1024;     // 98 scan chunks
    const int NB = (N + 511) / 512;          // 196 buckets

    // Workspace: csr[E]i2 | binned[E]u32 | h1b | h2b | deg | dinv |
    // row_start[N+1] | bucket_cursor[256] | totals | offsets  (~40 MB)
    char* p = (char*)d_ws;
    int2* csr = (int2*)p;                     p += (size_t)E * 8;
    unsigned int* binned = (unsigned int*)p;  p += (size_t)E * 4;
    unsigned short* h1b = (unsigned short*)p; p += (size_t)N * 64 * 2;
    unsigned short* h2b = (unsigned short*)p; p += (size_t)N * 32 * 2;
    unsigned int* deg = (unsigned int*)p;     p += (size_t)N * 4;
    float* dinv = (float*)p;                  p += (size_t)N * 4;
    int* row_start = (int*)p;                 p += (size_t)(N + 1) * 4;
    unsigned int* bucket_cursor = (unsigned int*)p; p += 256 * 4;
    unsigned int* totals = (unsigned int*)p;  p += 128 * 4;
    unsigned int* offsets = (unsigned int*)p;

    hipMemsetAsync(deg, 0, (size_t)N * sizeof(unsigned int), stream);

    hist_kernel<<<(E + 255) / 256, 256, 0, stream>>>(ei + E, E, deg);
    dinv_kernel<<<(N + 255) / 256, 256, 0, stream>>>(deg, dinv, N);
    scanA_kernel<<<NBLK, 256, 0, stream>>>(deg, N, totals);
    scanB_kernel<<<1, 128, 0, stream>>>(totals, NBLK, offsets, row_start, N, E);
    scanC_kernel<<<NBLK, 256, 0, stream>>>(deg, offsets, N, row_start, bucket_cursor);
    bin_kernel<<<(E + 4095) / 4096, 256, 0, stream>>>(ei, E, bucket_cursor, binned);
    place_kernel<<<NB, 1024, 0, stream>>>(binned, row_start, dinv, csr, N);

    gemm1_kernel<<<N / 16, 256, 0, stream>>>(x, W1, h1b, N);
    agg1_kernel<<<(N + 3) / 4, 256, 0, stream>>>((const unsigned int*)h1b, csr, row_start,
                                                 dinv, b1, W2, h2b, N);
    agg2_kernel<<<(N * 32 + 255) / 256, 256, 0, stream>>>((const unsigned int*)h2b, csr,
                                                          row_start, dinv, b2, out, N);
}

// Round 6
// 336.889 us; speedup vs baseline: 1.1526x; 1.1526x over previous
//
#include <hip/hip_runtime.h>

#define N_NODES 100000

// ---- bf16 helpers (manual, RNE) -------------------------------------------
__device__ __forceinline__ unsigned short f2bf_rn(float f) {
    unsigned int b = __float_as_uint(f);
    b += 0x7fffu + ((b >> 16) & 1u);
    return (unsigned short)(b >> 16);
}
__device__ __forceinline__ float bf_lo(unsigned int u) { return __uint_as_float(u << 16); }
__device__ __forceinline__ float bf_hi(unsigned int u) { return __uint_as_float(u & 0xffff0000u); }

// ============================ degree + dinv ================================

__global__ __launch_bounds__(256) void hist_kernel(const int* __restrict__ dst, int E,
                                                   unsigned int* __restrict__ deg) {
    int i = blockIdx.x * 256 + threadIdx.x;
    if (i < E) atomicAdd(&deg[dst[i]], 1u);
}

__global__ __launch_bounds__(256) void dinv_kernel(const unsigned int* __restrict__ deg,
                                                   float* __restrict__ dinv, int n) {
    int i = blockIdx.x * 256 + threadIdx.x;
    if (i < n) dinv[i] = rsqrtf((float)deg[i] + 1.0f);
}

// ======================= row_start = exclusive scan(deg) ===================

__global__ __launch_bounds__(256) void scanA_kernel(const unsigned int* __restrict__ deg,
                                                    int n, unsigned int* __restrict__ totals) {
    __shared__ unsigned int s[256];
    int t = threadIdx.x;
    int base = blockIdx.x * 1024 + t * 4;
    unsigned int sum = 0;
#pragma unroll
    for (int k = 0; k < 4; ++k) { int i = base + k; if (i < n) sum += deg[i]; }
    s[t] = sum; __syncthreads();
    for (int off = 128; off > 0; off >>= 1) {
        if (t < off) s[t] += s[t + off];
        __syncthreads();
    }
    if (t == 0) totals[blockIdx.x] = s[0];
}

__global__ __launch_bounds__(128) void scanB_kernel(const unsigned int* __restrict__ totals,
                                                    int nblk, unsigned int* __restrict__ offsets,
                                                    int* __restrict__ row_start, int n, int E) {
    __shared__ unsigned int s[128];
    int t = threadIdx.x;
    unsigned int v = (t < nblk) ? totals[t] : 0u;
    s[t] = v; __syncthreads();
    for (int off = 1; off < 128; off <<= 1) {
        unsigned int x = s[t];
        unsigned int y = (t >= off) ? s[t - off] : 0u;
        __syncthreads();
        s[t] = x + y;
        __syncthreads();
    }
    if (t < nblk) offsets[t] = s[t] - v;
    if (t == 0) row_start[n] = E;
}

// scanC also emits bucket_cursor[b] = row_start[b*512] (bin bucket bases)
__global__ __launch_bounds__(256) void scanC_kernel(const unsigned int* __restrict__ deg,
                                                    const unsigned int* __restrict__ offsets,
                                                    int n, int* __restrict__ row_start,
                                                    unsigned int* __restrict__ bucket_cursor) {
    __shared__ unsigned int s[256];
    int t = threadIdx.x;
    int base = blockIdx.x * 1024 + t * 4;
    unsigned int v[4];
    unsigned int sum = 0;
#pragma unroll
    for (int k = 0; k < 4; ++k) { int i = base + k; v[k] = (i < n) ? deg[i] : 0u; sum += v[k]; }
    s[t] = sum; __syncthreads();
    for (int off = 1; off < 256; off <<= 1) {
        unsigned int x = s[t];
        unsigned int y = (t >= off) ? s[t - off] : 0u;
        __syncthreads();
        s[t] = x + y;
        __syncthreads();
    }
    unsigned int excl = s[t] - sum + offsets[blockIdx.x];
#pragma unroll
    for (int k = 0; k < 4; ++k) {
        int i = base + k;
        if (i < n) {
            row_start[i] = (int)excl;
            if ((i & 511) == 0) bucket_cursor[i >> 9] = excl;
        }
        excl += v[k];
    }
}

// =================== bin: group edges by 512-node bucket ===================
__global__ __launch_bounds__(256) void bin_kernel(const int* __restrict__ ei, int E,
                                                  unsigned int* __restrict__ bucket_cursor,
                                                  unsigned int* __restrict__ binned) {
    __shared__ unsigned int cnt[256];
    __shared__ unsigned int cur[256];
    int t = threadIdx.x;
    cnt[t] = 0;
    __syncthreads();
    int base = blockIdx.x * 4096;
    unsigned int pk[16];
    unsigned int bk[16];
#pragma unroll
    for (int k = 0; k < 16; ++k) {
        int e = base + k * 256 + t;
        if (e < E) {
            int s = __builtin_nontemporal_load(&ei[e]);
            int d = __builtin_nontemporal_load(&ei[E + e]);
            unsigned int b = (unsigned int)d >> 9;
            pk[k] = (unsigned int)s | (((unsigned int)d & 511u) << 17);
            bk[k] = b;
            atomicAdd(&cnt[b], 1u);
        } else {
            bk[k] = 0xFFFFFFFFu;
        }
    }
    __syncthreads();
    if (cnt[t] > 0) cur[t] = atomicAdd(&bucket_cursor[t], cnt[t]);
    __syncthreads();
#pragma unroll
    for (int k = 0; k < 16; ++k) {
        if (bk[k] != 0xFFFFFFFFu) {
            unsigned int pos = atomicAdd(&cur[bk[k]], 1u);
            binned[pos] = pk[k];
        }
    }
}

// ============ place: one block per bucket -> final CSR (src, norm) =========
__global__ __launch_bounds__(1024) void place_kernel(const unsigned int* __restrict__ binned,
                                                     const int* __restrict__ row_start,
                                                     const float* __restrict__ dinv,
                                                     int2* __restrict__ csr, int N) {
    __shared__ int cur[512];
    __shared__ float dv[512];
    int t = threadIdx.x;
    int node0 = blockIdx.x << 9;
    if (t < 512) {
        int idx = node0 + t;
        int g = idx < N ? idx : N;
        cur[t] = row_start[g];
        dv[t] = dinv[idx < N ? idx : (N - 1)];
    }
    int endn = node0 + 512; if (endn > N) endn = N;
    int beg = row_start[node0];
    int end = row_start[endn];
    __syncthreads();
    for (int i = beg + t; i < end; i += 1024) {
        unsigned int u = __builtin_nontemporal_load(&binned[i]);
        int s = (int)(u & 0x1FFFFu);
        int doff = (int)(u >> 17);
        int slot = atomicAdd(&cur[doff], 1);
        int2 ent; ent.x = s; ent.y = __float_as_int(dinv[s] * dv[doff]);
        csr[slot] = ent;
    }
}

// ==================== GEMM1: h1[N,64](bf16) = x @ W1 =======================
__global__ __launch_bounds__(256) void gemm1_kernel(
    const float* __restrict__ x, const float* __restrict__ W,
    unsigned short* __restrict__ h1b, int N) {
    __shared__ float Ws[128 * 64];
    __shared__ float xs[16 * 128];
    int tid = threadIdx.x;
    const float4* W4 = (const float4*)W;
    float4* Ws4 = (float4*)Ws;
#pragma unroll
    for (int i = 0; i < 8; ++i) Ws4[tid + 256 * i] = W4[tid + 256 * i];
    int row0 = blockIdx.x * 16;
    const float4* x4 = (const float4*)(x + (size_t)row0 * 128);
    float4* xs4 = (float4*)xs;
#pragma unroll
    for (int i = 0; i < 2; ++i) xs4[tid + 256 * i] = x4[tid + 256 * i];
    __syncthreads();
    int j = tid & 63;
    int rg = tid >> 6;
    float acc0 = 0.f, acc1 = 0.f, acc2 = 0.f, acc3 = 0.f;
#pragma unroll 8
    for (int k = 0; k < 128; ++k) {
        float w = Ws[k * 64 + j];
        acc0 += xs[(rg + 0) * 128 + k] * w;
        acc1 += xs[(rg + 4) * 128 + k] * w;
        acc2 += xs[(rg + 8) * 128 + k] * w;
        acc3 += xs[(rg + 12) * 128 + k] * w;
    }
    float accs[4] = {acc0, acc1, acc2, acc3};
#pragma unroll
    for (int i = 0; i < 4; ++i) {
        int r = row0 + rg + i * 4;
        h1b[(size_t)r * 64 + j] = f2bf_rn(accs[i]);
    }
}

// ============ Aggregation 1 (+bias+relu) fused with GEMM2 ==================
// Round-4 mapping (32 lanes/node, 8 nodes/block) + batched deep prefetch:
// batches of 8 edges issue 8 csr loads then 8 independent gathers -> ~2
// latency waves per deg-16 row instead of ~8. csr loads are plain cached
// (half-wave broadcast, same line).
__global__ __launch_bounds__(256) void agg1_kernel(
    const unsigned int* __restrict__ h1u,   // [N,32] bf16-pairs
    const int2* __restrict__ csr,
    const int* __restrict__ row_start, const float* __restrict__ dinv,
    const float* __restrict__ b1, const float* __restrict__ W2,
    unsigned short* __restrict__ h2b, int N) {
    __shared__ float W2s[64 * 32];
    __shared__ float hr[8][64];
    int tid = threadIdx.x;
    const float4* W24 = (const float4*)W2;
    float4* W2s4 = (float4*)W2s;
#pragma unroll
    for (int i = 0; i < 2; ++i) W2s4[tid + 256 * i] = W24[tid + 256 * i];
    __syncthreads();
    int nib = tid >> 5;           // node-in-block 0..7
    int jp = tid & 31;            // feature pair
    int d = blockIdx.x * 8 + nib;
    if (d >= N) return;           // no barriers after this point
    float di = dinv[d];
    float2 bias = ((const float2*)b1)[jp];
    unsigned int su = h1u[(size_t)d * 32 + jp];
    int beg = row_start[d], end = row_start[d + 1];
    float a0 = bf_lo(su) * di * di;   // self-loop
    float a1 = bf_hi(su) * di * di;
    int e = beg;
    for (; e + 8 <= end; e += 8) {    // batch-8: 8 gathers in flight
        int2 c[8];
#pragma unroll
        for (int k = 0; k < 8; ++k) c[k] = csr[e + k];
        unsigned int u[8];
#pragma unroll
        for (int k = 0; k < 8; ++k) u[k] = h1u[(size_t)c[k].x * 32 + jp];
#pragma unroll
        for (int k = 0; k < 8; ++k) {
            float n = __int_as_float(c[k].y);
            a0 += bf_lo(u[k]) * n; a1 += bf_hi(u[k]) * n;
        }
    }
    if (e + 4 <= end) {               // batch-4 tier
        int2 c[4];
#pragma unroll
        for (int k = 0; k < 4; ++k) c[k] = csr[e + k];
        unsigned int u[4];
#pragma unroll
        for (int k = 0; k < 4; ++k) u[k] = h1u[(size_t)c[k].x * 32 + jp];
#pragma unroll
        for (int k = 0; k < 4; ++k) {
            float n = __int_as_float(c[k].y);
            a0 += bf_lo(u[k]) * n; a1 += bf_hi(u[k]) * n;
        }
        e += 4;
    }
    for (; e < end; ++e) {            // tail <=3
        int2 c0 = csr[e];
        unsigned int u0 = h1u[(size_t)c0.x * 32 + jp];
        float n0 = __int_as_float(c0.y);
        a0 += bf_lo(u0) * n0; a1 += bf_hi(u0) * n0;
    }
    float h0 = a0 + bias.x; h0 = fmaxf(h0, 0.f);
    float h1v = a1 + bias.y; h1v = fmaxf(h1v, 0.f);
    hr[nib][2 * jp] = h0;             // intra-wave LDS RAW, lgkmcnt-ordered
    hr[nib][2 * jp + 1] = h1v;
    const float* hrw = hr[nib];
    float p = 0.f;
#pragma unroll 8
    for (int k = 0; k < 64; ++k)
        p += hrw[k] * W2s[k * 32 + jp];
    h2b[(size_t)d * 32 + jp] = f2bf_rn(p);
}

// ===================== Aggregation 2 -> out (final layer) ==================
// 16 lanes per node, batched deep prefetch like agg1.
__global__ __launch_bounds__(256) void agg2_kernel(
    const unsigned int* __restrict__ h2u,   // [N,16] bf16-pairs
    const int2* __restrict__ csr,
    const int* __restrict__ row_start, const float* __restrict__ dinv,
    const float* __restrict__ b2, float* __restrict__ out, int N) {
    int t = blockIdx.x * 256 + threadIdx.x;
    int d = t >> 4;
    int jp = t & 15;
    if (d >= N) return;
    float di = dinv[d];
    float2 bias = ((const float2*)b2)[jp];
    unsigned int su = h2u[(size_t)d * 16 + jp];
    int beg = row_start[d], end = row_start[d + 1];
    float a0 = bf_lo(su) * di * di + bias.x;
    float a1 = bf_hi(su) * di * di + bias.y;
    int e = beg;
    for (; e + 8 <= end; e += 8) {
        int2 c[8];
#pragma unroll
        for (int k = 0; k < 8; ++k) c[k] = csr[e + k];
        unsigned int u[8];
#pragma unroll
        for (int k = 0; k < 8; ++k) u[k] = h2u[(size_t)c[k].x * 16 + jp];
#pragma unroll
        for (int k = 0; k < 8; ++k) {
            float n = __int_as_float(c[k].y);
            a0 += bf_lo(u[k]) * n; a1 += bf_hi(u[k]) * n;
        }
    }
    if (e + 4 <= end) {
        int2 c[4];
#pragma unroll
        for (int k = 0; k < 4; ++k) c[k] = csr[e + k];
        unsigned int u[4];
#pragma unroll
        for (int k = 0; k < 4; ++k) u[k] = h2u[(size_t)c[k].x * 16 + jp];
#pragma unroll
        for (int k = 0; k < 4; ++k) {
            float n = __int_as_float(c[k].y);
            a0 += bf_lo(u[k]) * n; a1 += bf_hi(u[k]) * n;
        }
        e += 4;
    }
    for (; e < end; ++e) {
        int2 c0 = csr[e];
        unsigned int u0 = h2u[(size_t)c0.x * 16 + jp];
        float n0 = __int_as_float(c0.y);
        a0 += bf_lo(u0) * n0; a1 += bf_hi(u0) * n0;
    }
    float2 r; r.x = a0; r.y = a1;
    ((float2*)(out + (size_t)d * 32))[jp] = r;
}

extern "C" void kernel_launch(void* const* d_in, const int* in_sizes, int n_in,
                              void* d_out, int out_size, void* d_ws, size_t ws_size,
                              hipStream_t stream) {
    const float* x  = (const float*)d_in[0];
    const int*   ei = (const int*)d_in[1];
    const float* W1 = (const float*)d_in[2];
    const float* b1 = (const float*)d_in[3];
    const float* W2 = (const float*)d_in[4];
    const float* b2 = (const float*)d_in[5];
    float* out = (float*)d_out;

    const int N = N_NODES;
    const int E = in_sizes[1] / 2;
    const int NBLK = (N + 1023) / 1024;     // 98 scan chunks
    const int NB = (N + 511) / 512;          // 196 buckets

    // Workspace: csr[E]i2 | binned[E]u32 | h1b | h2b | deg | dinv |
    // row_start[N+1] | bucket_cursor[256] | totals | offsets  (~40 MB)
    char* p = (char*)d_ws;
    int2* csr = (int2*)p;                     p += (size_t)E * 8;
    unsigned int* binned = (unsigned int*)p;  p += (size_t)E * 4;
    unsigned short* h1b = (unsigned short*)p; p += (size_t)N * 64 * 2;
    unsigned short* h2b = (unsigned short*)p; p += (size_t)N * 32 * 2;
    unsigned int* deg = (unsigned int*)p;     p += (size_t)N * 4;
    float* dinv = (float*)p;                  p += (size_t)N * 4;
    int* row_start = (int*)p;                 p += (size_t)(N + 1) * 4;
    unsigned int* bucket_cursor = (unsigned int*)p; p += 256 * 4;
    unsigned int* totals = (unsigned int*)p;  p += 128 * 4;
    unsigned int* offsets = (unsigned int*)p;

    hipMemsetAsync(deg, 0, (size_t)N * sizeof(unsigned int), stream);

    hist_kernel<<<(E + 255) / 256, 256, 0, stream>>>(ei + E, E, deg);
    dinv_kernel<<<(N + 255) / 256, 256, 0, stream>>>(deg, dinv, N);
    scanA_kernel<<<NBLK, 256, 0, stream>>>(deg, N, totals);
    scanB_kernel<<<1, 128, 0, stream>>>(totals, NBLK, offsets, row_start, N, E);
    scanC_kernel<<<NBLK, 256, 0, stream>>>(deg, offsets, N, row_start, bucket_cursor);
    bin_kernel<<<(E + 4095) / 4096, 256, 0, stream>>>(ei, E, bucket_cursor, binned);
    place_kernel<<<NB, 1024, 0, stream>>>(binned, row_start, dinv, csr, N);

    gemm1_kernel<<<N / 16, 256, 0, stream>>>(x, W1, h1b, N);
    agg1_kernel<<<(N + 7) / 8, 256, 0, stream>>>((const unsigned int*)h1b, csr, row_start,
                                                 dinv, b1, W2, h2b, N);
    agg2_kernel<<<(N * 16 + 255) / 256, 256, 0, stream>>>((const unsigned int*)h2b, csr,
                                                          row_start, dinv, b2, out, N);
}

// Round 7
// 306.374 us; speedup vs baseline: 1.2674x; 1.0996x over previous
//
#include <hip/hip_runtime.h>

#define N_NODES 100000

// ---- bf16 helpers (manual, RNE) -------------------------------------------
__device__ __forceinline__ unsigned short f2bf_rn(float f) {
    unsigned int b = __float_as_uint(f);
    b += 0x7fffu + ((b >> 16) & 1u);
    return (unsigned short)(b >> 16);
}
__device__ __forceinline__ float bf_lo(unsigned int u) { return __uint_as_float(u << 16); }
__device__ __forceinline__ float bf_hi(unsigned int u) { return __uint_as_float(u & 0xffff0000u); }

// ================= bucket count: LDS hist -> few global atomics ============
// Block = 4096 edges; bucket = dst>>9 (196 buckets). Global atomic traffic:
// <=196 per block (~76K total) instead of 1.6M node-grain atomics.
__global__ __launch_bounds__(256) void bcount_kernel(const int* __restrict__ dst, int E,
                                                     unsigned int* __restrict__ bucket_totals) {
    __shared__ unsigned int cnt[256];
    int t = threadIdx.x;
    cnt[t] = 0;
    __syncthreads();
    int base = blockIdx.x * 4096;
#pragma unroll
    for (int k = 0; k < 16; ++k) {
        int e = base + k * 256 + t;
        if (e < E) {
            int d = __builtin_nontemporal_load(&dst[e]);
            atomicAdd(&cnt[(unsigned int)d >> 9], 1u);
        }
    }
    __syncthreads();
    if (cnt[t] > 0) atomicAdd(&bucket_totals[t], cnt[t]);
}

// ============ bucket scan: 196 totals -> bucket_base / bucket_cursor =======
__global__ __launch_bounds__(256) void bscan_kernel(const unsigned int* __restrict__ totals,
                                                    int nb, int E,
                                                    unsigned int* __restrict__ bucket_base,
                                                    unsigned int* __restrict__ bucket_cursor) {
    __shared__ unsigned int s[256];
    int t = threadIdx.x;
    unsigned int v = (t < nb) ? totals[t] : 0u;
    s[t] = v; __syncthreads();
    for (int off = 1; off < 256; off <<= 1) {
        unsigned int x = s[t];
        unsigned int y = (t >= off) ? s[t - off] : 0u;
        __syncthreads();
        s[t] = x + y;
        __syncthreads();
    }
    if (t < nb) {
        unsigned int excl = s[t] - v;
        bucket_base[t] = excl;
        bucket_cursor[t] = excl;
    }
    if (t == 0) bucket_base[nb] = (unsigned int)E;
}

// =================== bin: group edges by 512-node bucket ===================
// Entry: src (17b) | dst&511 (9b)<<17.
__global__ __launch_bounds__(256) void bin_kernel(const int* __restrict__ ei, int E,
                                                  unsigned int* __restrict__ bucket_cursor,
                                                  unsigned int* __restrict__ binned) {
    __shared__ unsigned int cnt[256];
    __shared__ unsigned int cur[256];
    int t = threadIdx.x;
    cnt[t] = 0;
    __syncthreads();
    int base = blockIdx.x * 4096;
    unsigned int pk[16];
    unsigned int bk[16];
#pragma unroll
    for (int k = 0; k < 16; ++k) {
        int e = base + k * 256 + t;
        if (e < E) {
            int s = __builtin_nontemporal_load(&ei[e]);
            int d = __builtin_nontemporal_load(&ei[E + e]);
            unsigned int b = (unsigned int)d >> 9;
            pk[k] = (unsigned int)s | (((unsigned int)d & 511u) << 17);
            bk[k] = b;
            atomicAdd(&cnt[b], 1u);
        } else {
            bk[k] = 0xFFFFFFFFu;
        }
    }
    __syncthreads();
    if (cnt[t] > 0) cur[t] = atomicAdd(&bucket_cursor[t], cnt[t]);
    __syncthreads();
#pragma unroll
    for (int k = 0; k < 16; ++k) {
        if (bk[k] != 0xFFFFFFFFu) {
            unsigned int pos = atomicAdd(&cur[bk[k]], 1u);
            binned[pos] = pk[k];
        }
    }
}

// ==== degb: per-bucket LDS histogram of binned -> dense deg + dinv write ===
__global__ __launch_bounds__(512) void degb_kernel(const unsigned int* __restrict__ binned,
                                                   const unsigned int* __restrict__ bucket_base,
                                                   unsigned int* __restrict__ deg,
                                                   float* __restrict__ dinv, int N) {
    __shared__ unsigned int cnt[512];
    int t = threadIdx.x;
    cnt[t] = 0;
    int beg = (int)bucket_base[blockIdx.x];
    int end = (int)bucket_base[blockIdx.x + 1];
    __syncthreads();
    for (int i = beg + t; i < end; i += 512) {
        unsigned int u = __builtin_nontemporal_load(&binned[i]);
        atomicAdd(&cnt[u >> 17], 1u);
    }
    __syncthreads();
    int node = (blockIdx.x << 9) + t;
    if (node < N) {
        unsigned int c = cnt[t];
        deg[node] = c;
        dinv[node] = rsqrtf((float)c + 1.0f);
    }
}

// ======================= row_start = exclusive scan(deg) ===================

__global__ __launch_bounds__(256) void scanA_kernel(const unsigned int* __restrict__ deg,
                                                    int n, unsigned int* __restrict__ totals) {
    __shared__ unsigned int s[256];
    int t = threadIdx.x;
    int base = blockIdx.x * 1024 + t * 4;
    unsigned int sum = 0;
#pragma unroll
    for (int k = 0; k < 4; ++k) { int i = base + k; if (i < n) sum += deg[i]; }
    s[t] = sum; __syncthreads();
    for (int off = 128; off > 0; off >>= 1) {
        if (t < off) s[t] += s[t + off];
        __syncthreads();
    }
    if (t == 0) totals[blockIdx.x] = s[0];
}

__global__ __launch_bounds__(128) void scanB_kernel(const unsigned int* __restrict__ totals,
                                                    int nblk, unsigned int* __restrict__ offsets,
                                                    int* __restrict__ row_start, int n, int E) {
    __shared__ unsigned int s[128];
    int t = threadIdx.x;
    unsigned int v = (t < nblk) ? totals[t] : 0u;
    s[t] = v; __syncthreads();
    for (int off = 1; off < 128; off <<= 1) {
        unsigned int x = s[t];
        unsigned int y = (t >= off) ? s[t - off] : 0u;
        __syncthreads();
        s[t] = x + y;
        __syncthreads();
    }
    if (t < nblk) offsets[t] = s[t] - v;
    if (t == 0) row_start[n] = E;
}

__global__ __launch_bounds__(256) void scanC_kernel(const unsigned int* __restrict__ deg,
                                                    const unsigned int* __restrict__ offsets,
                                                    int n, int* __restrict__ row_start) {
    __shared__ unsigned int s[256];
    int t = threadIdx.x;
    int base = blockIdx.x * 1024 + t * 4;
    unsigned int v[4];
    unsigned int sum = 0;
#pragma unroll
    for (int k = 0; k < 4; ++k) { int i = base + k; v[k] = (i < n) ? deg[i] : 0u; sum += v[k]; }
    s[t] = sum; __syncthreads();
    for (int off = 1; off < 256; off <<= 1) {
        unsigned int x = s[t];
        unsigned int y = (t >= off) ? s[t - off] : 0u;
        __syncthreads();
        s[t] = x + y;
        __syncthreads();
    }
    unsigned int excl = s[t] - sum + offsets[blockIdx.x];
#pragma unroll
    for (int k = 0; k < 4; ++k) {
        int i = base + k;
        if (i < n) row_start[i] = (int)excl;
        excl += v[k];
    }
}

// ============ place: one block per bucket -> final CSR (src, norm) =========
// row_start[b*512] == bucket_base[b] by construction, so the bucket's binned
// range equals its csr range.
__global__ __launch_bounds__(1024) void place_kernel(const unsigned int* __restrict__ binned,
                                                     const int* __restrict__ row_start,
                                                     const float* __restrict__ dinv,
                                                     int2* __restrict__ csr, int N) {
    __shared__ int cur[512];
    __shared__ float dv[512];
    int t = threadIdx.x;
    int node0 = blockIdx.x << 9;
    if (t < 512) {
        int idx = node0 + t;
        int g = idx < N ? idx : N;
        cur[t] = row_start[g];
        dv[t] = dinv[idx < N ? idx : (N - 1)];
    }
    int endn = node0 + 512; if (endn > N) endn = N;
    int beg = row_start[node0];
    int end = row_start[endn];
    __syncthreads();
    for (int i = beg + t; i < end; i += 1024) {
        unsigned int u = __builtin_nontemporal_load(&binned[i]);
        int s = (int)(u & 0x1FFFFu);
        int doff = (int)(u >> 17);
        int slot = atomicAdd(&cur[doff], 1);
        int2 ent; ent.x = s; ent.y = __float_as_int(dinv[s] * dv[doff]);
        csr[slot] = ent;
    }
}

// ==================== GEMM1: h1[N,64](bf16) = x @ W1 =======================
__global__ __launch_bounds__(256) void gemm1_kernel(
    const float* __restrict__ x, const float* __restrict__ W,
    unsigned short* __restrict__ h1b, int N) {
    __shared__ float Ws[128 * 64];
    __shared__ float xs[16 * 128];
    int tid = threadIdx.x;
    const float4* W4 = (const float4*)W;
    float4* Ws4 = (float4*)Ws;
#pragma unroll
    for (int i = 0; i < 8; ++i) Ws4[tid + 256 * i] = W4[tid + 256 * i];
    int row0 = blockIdx.x * 16;
    const float4* x4 = (const float4*)(x + (size_t)row0 * 128);
    float4* xs4 = (float4*)xs;
#pragma unroll
    for (int i = 0; i < 2; ++i) xs4[tid + 256 * i] = x4[tid + 256 * i];
    __syncthreads();
    int j = tid & 63;
    int rg = tid >> 6;
    float acc0 = 0.f, acc1 = 0.f, acc2 = 0.f, acc3 = 0.f;
#pragma unroll 8
    for (int k = 0; k < 128; ++k) {
        float w = Ws[k * 64 + j];
        acc0 += xs[(rg + 0) * 128 + k] * w;
        acc1 += xs[(rg + 4) * 128 + k] * w;
        acc2 += xs[(rg + 8) * 128 + k] * w;
        acc3 += xs[(rg + 12) * 128 + k] * w;
    }
    float accs[4] = {acc0, acc1, acc2, acc3};
#pragma unroll
    for (int i = 0; i < 4; ++i) {
        int r = row0 + rg + i * 4;
        h1b[(size_t)r * 64 + j] = f2bf_rn(accs[i]);
    }
}

// ============ Aggregation 1 (+bias+relu) fused with GEMM2 ==================
// 32 lanes/node, 8 nodes/block, batch-8 deep prefetch (8 gathers in flight).
__global__ __launch_bounds__(256) void agg1_kernel(
    const unsigned int* __restrict__ h1u,   // [N,32] bf16-pairs
    const int2* __restrict__ csr,
    const int* __restrict__ row_start, const float* __restrict__ dinv,
    const float* __restrict__ b1, const float* __restrict__ W2,
    unsigned short* __restrict__ h2b, int N) {
    __shared__ float W2s[64 * 32];
    __shared__ float hr[8][64];
    int tid = threadIdx.x;
    const float4* W24 = (const float4*)W2;
    float4* W2s4 = (float4*)W2s;
#pragma unroll
    for (int i = 0; i < 2; ++i) W2s4[tid + 256 * i] = W24[tid + 256 * i];
    __syncthreads();
    int nib = tid >> 5;           // node-in-block 0..7
    int jp = tid & 31;            // feature pair
    int d = blockIdx.x * 8 + nib;
    if (d >= N) return;           // no barriers after this point
    float di = dinv[d];
    float2 bias = ((const float2*)b1)[jp];
    unsigned int su = h1u[(size_t)d * 32 + jp];
    int beg = row_start[d], end = row_start[d + 1];
    float a0 = bf_lo(su) * di * di;   // self-loop
    float a1 = bf_hi(su) * di * di;
    int e = beg;
    for (; e + 8 <= end; e += 8) {    // batch-8: 8 gathers in flight
        int2 c[8];
#pragma unroll
        for (int k = 0; k < 8; ++k) c[k] = csr[e + k];
        unsigned int u[8];
#pragma unroll
        for (int k = 0; k < 8; ++k) u[k] = h1u[(size_t)c[k].x * 32 + jp];
#pragma unroll
        for (int k = 0; k < 8; ++k) {
            float n = __int_as_float(c[k].y);
            a0 += bf_lo(u[k]) * n; a1 += bf_hi(u[k]) * n;
        }
    }
    if (e + 4 <= end) {               // batch-4 tier
        int2 c[4];
#pragma unroll
        for (int k = 0; k < 4; ++k) c[k] = csr[e + k];
        unsigned int u[4];
#pragma unroll
        for (int k = 0; k < 4; ++k) u[k] = h1u[(size_t)c[k].x * 32 + jp];
#pragma unroll
        for (int k = 0; k < 4; ++k) {
            float n = __int_as_float(c[k].y);
            a0 += bf_lo(u[k]) * n; a1 += bf_hi(u[k]) * n;
        }
        e += 4;
    }
    for (; e < end; ++e) {            // tail <=3
        int2 c0 = csr[e];
        unsigned int u0 = h1u[(size_t)c0.x * 32 + jp];
        float n0 = __int_as_float(c0.y);
        a0 += bf_lo(u0) * n0; a1 += bf_hi(u0) * n0;
    }
    float h0 = a0 + bias.x; h0 = fmaxf(h0, 0.f);
    float h1v = a1 + bias.y; h1v = fmaxf(h1v, 0.f);
    hr[nib][2 * jp] = h0;             // intra-wave LDS RAW, lgkmcnt-ordered
    hr[nib][2 * jp + 1] = h1v;
    const float* hrw = hr[nib];
    float p = 0.f;
#pragma unroll 8
    for (int k = 0; k < 64; ++k)
        p += hrw[k] * W2s[k * 32 + jp];
    h2b[(size_t)d * 32 + jp] = f2bf_rn(p);
}

// ===================== Aggregation 2 -> out (final layer) ==================
__global__ __launch_bounds__(256) void agg2_kernel(
    const unsigned int* __restrict__ h2u,   // [N,16] bf16-pairs
    const int2* __restrict__ csr,
    const int* __restrict__ row_start, const float* __restrict__ dinv,
    const float* __restrict__ b2, float* __restrict__ out, int N) {
    int t = blockIdx.x * 256 + threadIdx.x;
    int d = t >> 4;
    int jp = t & 15;
    if (d >= N) return;
    float di = dinv[d];
    float2 bias = ((const float2*)b2)[jp];
    unsigned int su = h2u[(size_t)d * 16 + jp];
    int beg = row_start[d], end = row_start[d + 1];
    float a0 = bf_lo(su) * di * di + bias.x;
    float a1 = bf_hi(su) * di * di + bias.y;
    int e = beg;
    for (; e + 8 <= end; e += 8) {
        int2 c[8];
#pragma unroll
        for (int k = 0; k < 8; ++k) c[k] = csr[e + k];
        unsigned int u[8];
#pragma unroll
        for (int k = 0; k < 8; ++k) u[k] = h2u[(size_t)c[k].x * 16 + jp];
#pragma unroll
        for (int k = 0; k < 8; ++k) {
            float n = __int_as_float(c[k].y);
            a0 += bf_lo(u[k]) * n; a1 += bf_hi(u[k]) * n;
        }
    }
    if (e + 4 <= end) {
        int2 c[4];
#pragma unroll
        for (int k = 0; k < 4; ++k) c[k] = csr[e + k];
        unsigned int u[4];
#pragma unroll
        for (int k = 0; k < 4; ++k) u[k] = h2u[(size_t)c[k].x * 16 + jp];
#pragma unroll
        for (int k = 0; k < 4; ++k) {
            float n = __int_as_float(c[k].y);
            a0 += bf_lo(u[k]) * n; a1 += bf_hi(u[k]) * n;
        }
        e += 4;
    }
    for (; e < end; ++e) {
        int2 c0 = csr[e];
        unsigned int u0 = h2u[(size_t)c0.x * 16 + jp];
        float n0 = __int_as_float(c0.y);
        a0 += bf_lo(u0) * n0; a1 += bf_hi(u0) * n0;
    }
    float2 r; r.x = a0; r.y = a1;
    ((float2*)(out + (size_t)d * 32))[jp] = r;
}

extern "C" void kernel_launch(void* const* d_in, const int* in_sizes, int n_in,
                              void* d_out, int out_size, void* d_ws, size_t ws_size,
                              hipStream_t stream) {
    const float* x  = (const float*)d_in[0];
    const int*   ei = (const int*)d_in[1];
    const float* W1 = (const float*)d_in[2];
    const float* b1 = (const float*)d_in[3];
    const float* W2 = (const float*)d_in[4];
    const float* b2 = (const float*)d_in[5];
    float* out = (float*)d_out;

    const int N = N_NODES;
    const int E = in_sizes[1] / 2;
    const int NBLK = (N + 1023) / 1024;     // 98 scan chunks
    const int NB = (N + 511) / 512;          // 196 buckets
    const int EB = (E + 4095) / 4096;        // 391 edge blocks

    // Workspace: csr[E]i2 | binned[E]u32 | h1b | h2b | deg | dinv |
    // row_start[N+1] | bucket_totals[256] | bucket_base[256] |
    // bucket_cursor[256] | totals[128] | offsets[128]  (~40 MB)
    char* p = (char*)d_ws;
    int2* csr = (int2*)p;                     p += (size_t)E * 8;
    unsigned int* binned = (unsigned int*)p;  p += (size_t)E * 4;
    unsigned short* h1b = (unsigned short*)p; p += (size_t)N * 64 * 2;
    unsigned short* h2b = (unsigned short*)p; p += (size_t)N * 32 * 2;
    unsigned int* deg = (unsigned int*)p;     p += (size_t)N * 4;
    float* dinv = (float*)p;                  p += (size_t)N * 4;
    int* row_start = (int*)p;                 p += (size_t)(N + 1) * 4;
    unsigned int* bucket_totals = (unsigned int*)p; p += 256 * 4;
    unsigned int* bucket_base = (unsigned int*)p;   p += 256 * 4;
    unsigned int* bucket_cursor = (unsigned int*)p; p += 256 * 4;
    unsigned int* totals = (unsigned int*)p;  p += 128 * 4;
    unsigned int* offsets = (unsigned int*)p;

    hipMemsetAsync(bucket_totals, 0, 256 * sizeof(unsigned int), stream);

    bcount_kernel<<<EB, 256, 0, stream>>>(ei + E, E, bucket_totals);
    bscan_kernel<<<1, 256, 0, stream>>>(bucket_totals, NB, E, bucket_base, bucket_cursor);
    bin_kernel<<<EB, 256, 0, stream>>>(ei, E, bucket_cursor, binned);
    degb_kernel<<<NB, 512, 0, stream>>>(binned, bucket_base, deg, dinv, N);
    scanA_kernel<<<NBLK, 256, 0, stream>>>(deg, N, totals);
    scanB_kernel<<<1, 128, 0, stream>>>(totals, NBLK, offsets, row_start, N, E);
    scanC_kernel<<<NBLK, 256, 0, stream>>>(deg, offsets, N, row_start);
    place_kernel<<<NB, 1024, 0, stream>>>(binned, row_start, dinv, csr, N);

    gemm1_kernel<<<N / 16, 256, 0, stream>>>(x, W1, h1b, N);
    agg1_kernel<<<(N + 7) / 8, 256, 0, stream>>>((const unsigned int*)h1b, csr, row_start,
                                                 dinv, b1, W2, h2b, N);
    agg2_kernel<<<(N * 16 + 255) / 256, 256, 0, stream>>>((const unsigned int*)h2b, csr,
                                                          row_start, dinv, b2, out, N);
}

// Round 8
// 299.183 us; speedup vs baseline: 1.2978x; 1.0240x over previous
//
#include <hip/hip_runtime.h>

#define N_NODES 100000

// ---- bf16 helpers (manual, RNE) -------------------------------------------
__device__ __forceinline__ unsigned short f2bf_rn(float f) {
    unsigned int b = __float_as_uint(f);
    b += 0x7fffu + ((b >> 16) & 1u);
    return (unsigned short)(b >> 16);
}
__device__ __forceinline__ float bf_lo(unsigned int u) { return __uint_as_float(u << 16); }
__device__ __forceinline__ float bf_hi(unsigned int u) { return __uint_as_float(u & 0xffff0000u); }

// ================= bucket count: LDS hist -> few global atomics ============
__global__ __launch_bounds__(256) void bcount_kernel(const int* __restrict__ dst, int E,
                                                     unsigned int* __restrict__ bucket_totals) {
    __shared__ unsigned int cnt[256];
    int t = threadIdx.x;
    cnt[t] = 0;
    __syncthreads();
    int base = blockIdx.x * 4096;
#pragma unroll
    for (int k = 0; k < 16; ++k) {
        int e = base + k * 256 + t;
        if (e < E) {
            int d = __builtin_nontemporal_load(&dst[e]);
            atomicAdd(&cnt[(unsigned int)d >> 9], 1u);
        }
    }
    __syncthreads();
    if (cnt[t] > 0) atomicAdd(&bucket_totals[t], cnt[t]);
}

// ============ bucket scan: 196 totals -> bucket_base / bucket_cursor =======
__global__ __launch_bounds__(256) void bscan_kernel(const unsigned int* __restrict__ totals,
                                                    int nb, int E,
                                                    unsigned int* __restrict__ bucket_base,
                                                    unsigned int* __restrict__ bucket_cursor) {
    __shared__ unsigned int s[256];
    int t = threadIdx.x;
    unsigned int v = (t < nb) ? totals[t] : 0u;
    s[t] = v; __syncthreads();
    for (int off = 1; off < 256; off <<= 1) {
        unsigned int x = s[t];
        unsigned int y = (t >= off) ? s[t - off] : 0u;
        __syncthreads();
        s[t] = x + y;
        __syncthreads();
    }
    if (t < nb) {
        unsigned int excl = s[t] - v;
        bucket_base[t] = excl;
        bucket_cursor[t] = excl;
    }
    if (t == 0) bucket_base[nb] = (unsigned int)E;
}

// =================== bin: group edges by 512-node bucket ===================
__global__ __launch_bounds__(256) void bin_kernel(const int* __restrict__ ei, int E,
                                                  unsigned int* __restrict__ bucket_cursor,
                                                  unsigned int* __restrict__ binned) {
    __shared__ unsigned int cnt[256];
    __shared__ unsigned int cur[256];
    int t = threadIdx.x;
    cnt[t] = 0;
    __syncthreads();
    int base = blockIdx.x * 4096;
    unsigned int pk[16];
    unsigned int bk[16];
#pragma unroll
    for (int k = 0; k < 16; ++k) {
        int e = base + k * 256 + t;
        if (e < E) {
            int s = __builtin_nontemporal_load(&ei[e]);
            int d = __builtin_nontemporal_load(&ei[E + e]);
            unsigned int b = (unsigned int)d >> 9;
            pk[k] = (unsigned int)s | (((unsigned int)d & 511u) << 17);
            bk[k] = b;
            atomicAdd(&cnt[b], 1u);
        } else {
            bk[k] = 0xFFFFFFFFu;
        }
    }
    __syncthreads();
    if (cnt[t] > 0) cur[t] = atomicAdd(&bucket_cursor[t], cnt[t]);
    __syncthreads();
#pragma unroll
    for (int k = 0; k < 16; ++k) {
        if (bk[k] != 0xFFFFFFFFu) {
            unsigned int pos = atomicAdd(&cur[bk[k]], 1u);
            binned[pos] = pk[k];
        }
    }
}

// ==== degb: per-bucket LDS histogram of binned -> dense deg + dinv write ===
__global__ __launch_bounds__(512) void degb_kernel(const unsigned int* __restrict__ binned,
                                                   const unsigned int* __restrict__ bucket_base,
                                                   unsigned int* __restrict__ deg,
                                                   float* __restrict__ dinv, int N) {
    __shared__ unsigned int cnt[512];
    int t = threadIdx.x;
    cnt[t] = 0;
    int beg = (int)bucket_base[blockIdx.x];
    int end = (int)bucket_base[blockIdx.x + 1];
    __syncthreads();
    for (int i = beg + t; i < end; i += 512) {
        unsigned int u = __builtin_nontemporal_load(&binned[i]);
        atomicAdd(&cnt[u >> 17], 1u);
    }
    __syncthreads();
    int node = (blockIdx.x << 9) + t;
    if (node < N) {
        unsigned int c = cnt[t];
        deg[node] = c;
        dinv[node] = rsqrtf((float)c + 1.0f);
    }
}

// ======================= row_start = exclusive scan(deg) ===================

__global__ __launch_bounds__(256) void scanA_kernel(const unsigned int* __restrict__ deg,
                                                    int n, unsigned int* __restrict__ totals) {
    __shared__ unsigned int s[256];
    int t = threadIdx.x;
    int base = blockIdx.x * 1024 + t * 4;
    unsigned int sum = 0;
#pragma unroll
    for (int k = 0; k < 4; ++k) { int i = base + k; if (i < n) sum += deg[i]; }
    s[t] = sum; __syncthreads();
    for (int off = 128; off > 0; off >>= 1) {
        if (t < off) s[t] += s[t + off];
        __syncthreads();
    }
    if (t == 0) totals[blockIdx.x] = s[0];
}

__global__ __launch_bounds__(128) void scanB_kernel(const unsigned int* __restrict__ totals,
                                                    int nblk, unsigned int* __restrict__ offsets,
                                                    int* __restrict__ row_start, int n, int E) {
    __shared__ unsigned int s[128];
    int t = threadIdx.x;
    unsigned int v = (t < nblk) ? totals[t] : 0u;
    s[t] = v; __syncthreads();
    for (int off = 1; off < 128; off <<= 1) {
        unsigned int x = s[t];
        unsigned int y = (t >= off) ? s[t - off] : 0u;
        __syncthreads();
        s[t] = x + y;
        __syncthreads();
    }
    if (t < nblk) offsets[t] = s[t] - v;
    if (t == 0) row_start[n] = E;
}

__global__ __launch_bounds__(256) void scanC_kernel(const unsigned int* __restrict__ deg,
                                                    const unsigned int* __restrict__ offsets,
                                                    int n, int* __restrict__ row_start) {
    __shared__ unsigned int s[256];
    int t = threadIdx.x;
    int base = blockIdx.x * 1024 + t * 4;
    unsigned int v[4];
    unsigned int sum = 0;
#pragma unroll
    for (int k = 0; k < 4; ++k) { int i = base + k; v[k] = (i < n) ? deg[i] : 0u; sum += v[k]; }
    s[t] = sum; __syncthreads();
    for (int off = 1; off < 256; off <<= 1) {
        unsigned int x = s[t];
        unsigned int y = (t >= off) ? s[t - off] : 0u;
        __syncthreads();
        s[t] = x + y;
        __syncthreads();
    }
    unsigned int excl = s[t] - sum + offsets[blockIdx.x];
#pragma unroll
    for (int k = 0; k < 4; ++k) {
        int i = base + k;
        if (i < n) row_start[i] = (int)excl;
        excl += v[k];
    }
}

// ============ place: one block per bucket -> final CSR (src, norm) =========
__global__ __launch_bounds__(1024) void place_kernel(const unsigned int* __restrict__ binned,
                                                     const int* __restrict__ row_start,
                                                     const float* __restrict__ dinv,
                                                     int2* __restrict__ csr, int N) {
    __shared__ int cur[512];
    __shared__ float dv[512];
    int t = threadIdx.x;
    int node0 = blockIdx.x << 9;
    if (t < 512) {
        int idx = node0 + t;
        int g = idx < N ? idx : N;
        cur[t] = row_start[g];
        dv[t] = dinv[idx < N ? idx : (N - 1)];
    }
    int endn = node0 + 512; if (endn > N) endn = N;
    int beg = row_start[node0];
    int end = row_start[endn];
    __syncthreads();
    for (int i = beg + t; i < end; i += 1024) {
        unsigned int u = __builtin_nontemporal_load(&binned[i]);
        int s = (int)(u & 0x1FFFFu);
        int doff = (int)(u >> 17);
        int slot = atomicAdd(&cur[doff], 1);
        int2 ent; ent.x = s; ent.y = __float_as_int(dinv[s] * dv[doff]);
        csr[slot] = ent;
    }
}

// ==================== GEMM1: h1[N,64](bf16) = x @ W1 =======================
// 64-row tile, 256 threads, thread = 4 rows x 4 cols (register-blocked).
// All LDS reads are ds_read_b128: per 4-k-step 8 b128 reads feed 64 FMAs ->
// VALU-bound. xs rows padded to 132 floats (33 float4) so the 4 tr-broadcast
// addresses land on 2 bank-sets (2-way = free); Ws reads are 16 consecutive
// float4 = 64 dwords = 2-way (free).
__global__ __launch_bounds__(256) void gemm1_kernel(
    const float* __restrict__ x, const float* __restrict__ W,
    unsigned short* __restrict__ h1b, int N) {
    __shared__ float4 Ws4[128 * 16];     // W row-major k x 64 (16 float4/row)
    __shared__ float4 xs4[64 * 33];      // 64 rows x 132 floats (pad 4)
    int tid = threadIdx.x;
    const float4* W4 = (const float4*)W;
#pragma unroll
    for (int i = 0; i < 8; ++i) Ws4[tid + 256 * i] = W4[tid + 256 * i];
    int row0 = blockIdx.x * 64;
    const float4* x4 = (const float4*)x;
#pragma unroll
    for (int i = 0; i < 8; ++i) {
        int idx = tid + 256 * i;             // 2048 float4 = 64 rows x 32
        int r = idx >> 5, c = idx & 31;
        int gr = row0 + r;
        float4 v;
        if (gr < N) v = x4[(size_t)gr * 32 + c];
        else { v.x = v.y = v.z = v.w = 0.f; }
        xs4[r * 33 + c] = v;
    }
    __syncthreads();
    int tc = tid & 15;        // col group: cols tc*4..tc*4+3
    int tr = tid >> 4;        // row group: rows tr*4..tr*4+3
    float4 acc[4];
#pragma unroll
    for (int rr = 0; rr < 4; ++rr) { acc[rr].x = 0.f; acc[rr].y = 0.f; acc[rr].z = 0.f; acc[rr].w = 0.f; }
#pragma unroll 2
    for (int k4 = 0; k4 < 32; ++k4) {
        float4 xr[4], w[4];
#pragma unroll
        for (int rr = 0; rr < 4; ++rr) xr[rr] = xs4[(tr * 4 + rr) * 33 + k4];
#pragma unroll
        for (int kk = 0; kk < 4; ++kk) w[kk] = Ws4[(k4 * 4 + kk) * 16 + tc];
#pragma unroll
        for (int rr = 0; rr < 4; ++rr) {
            acc[rr].x += xr[rr].x * w[0].x; acc[rr].y += xr[rr].x * w[0].y;
            acc[rr].z += xr[rr].x * w[0].z; acc[rr].w += xr[rr].x * w[0].w;
            acc[rr].x += xr[rr].y * w[1].x; acc[rr].y += xr[rr].y * w[1].y;
            acc[rr].z += xr[rr].y * w[1].z; acc[rr].w += xr[rr].y * w[1].w;
            acc[rr].x += xr[rr].z * w[2].x; acc[rr].y += xr[rr].z * w[2].y;
            acc[rr].z += xr[rr].z * w[2].z; acc[rr].w += xr[rr].z * w[2].w;
            acc[rr].x += xr[rr].w * w[3].x; acc[rr].y += xr[rr].w * w[3].y;
            acc[rr].z += xr[rr].w * w[3].z; acc[rr].w += xr[rr].w * w[3].w;
        }
    }
#pragma unroll
    for (int rr = 0; rr < 4; ++rr) {
        int r = row0 + tr * 4 + rr;
        if (r < N) {
            ushort4 o;
            o.x = f2bf_rn(acc[rr].x); o.y = f2bf_rn(acc[rr].y);
            o.z = f2bf_rn(acc[rr].z); o.w = f2bf_rn(acc[rr].w);
            *(ushort4*)(h1b + (size_t)r * 64 + tc * 4) = o;   // 8B coalesced
        }
    }
}

// ============ Aggregation 1 (+bias+relu) fused with GEMM2 ==================
// 32 lanes/node, 8 nodes/block, batch-8 deep prefetch (8 gathers in flight).
__global__ __launch_bounds__(256) void agg1_kernel(
    const unsigned int* __restrict__ h1u,   // [N,32] bf16-pairs
    const int2* __restrict__ csr,
    const int* __restrict__ row_start, const float* __restrict__ dinv,
    const float* __restrict__ b1, const float* __restrict__ W2,
    unsigned short* __restrict__ h2b, int N) {
    __shared__ float W2s[64 * 32];
    __shared__ float hr[8][64];
    int tid = threadIdx.x;
    const float4* W24 = (const float4*)W2;
    float4* W2s4 = (float4*)W2s;
#pragma unroll
    for (int i = 0; i < 2; ++i) W2s4[tid + 256 * i] = W24[tid + 256 * i];
    __syncthreads();
    int nib = tid >> 5;           // node-in-block 0..7
    int jp = tid & 31;            // feature pair
    int d = blockIdx.x * 8 + nib;
    if (d >= N) return;           // no barriers after this point
    float di = dinv[d];
    float2 bias = ((const float2*)b1)[jp];
    unsigned int su = h1u[(size_t)d * 32 + jp];
    int beg = row_start[d], end = row_start[d + 1];
    float a0 = bf_lo(su) * di * di;   // self-loop
    float a1 = bf_hi(su) * di * di;
    int e = beg;
    for (; e + 8 <= end; e += 8) {    // batch-8: 8 gathers in flight
        int2 c[8];
#pragma unroll
        for (int k = 0; k < 8; ++k) c[k] = csr[e + k];
        unsigned int u[8];
#pragma unroll
        for (int k = 0; k < 8; ++k) u[k] = h1u[(size_t)c[k].x * 32 + jp];
#pragma unroll
        for (int k = 0; k < 8; ++k) {
            float n = __int_as_float(c[k].y);
            a0 += bf_lo(u[k]) * n; a1 += bf_hi(u[k]) * n;
        }
    }
    if (e + 4 <= end) {               // batch-4 tier
        int2 c[4];
#pragma unroll
        for (int k = 0; k < 4; ++k) c[k] = csr[e + k];
        unsigned int u[4];
#pragma unroll
        for (int k = 0; k < 4; ++k) u[k] = h1u[(size_t)c[k].x * 32 + jp];
#pragma unroll
        for (int k = 0; k < 4; ++k) {
            float n = __int_as_float(c[k].y);
            a0 += bf_lo(u[k]) * n; a1 += bf_hi(u[k]) * n;
        }
        e += 4;
    }
    for (; e < end; ++e) {            // tail <=3
        int2 c0 = csr[e];
        unsigned int u0 = h1u[(size_t)c0.x * 32 + jp];
        float n0 = __int_as_float(c0.y);
        a0 += bf_lo(u0) * n0; a1 += bf_hi(u0) * n0;
    }
    float h0 = a0 + bias.x; h0 = fmaxf(h0, 0.f);
    float h1v = a1 + bias.y; h1v = fmaxf(h1v, 0.f);
    hr[nib][2 * jp] = h0;             // intra-wave LDS RAW, lgkmcnt-ordered
    hr[nib][2 * jp + 1] = h1v;
    const float* hrw = hr[nib];
    float p = 0.f;
#pragma unroll 8
    for (int k = 0; k < 64; ++k)
        p += hrw[k] * W2s[k * 32 + jp];
    h2b[(size_t)d * 32 + jp] = f2bf_rn(p);
}

// ===================== Aggregation 2 -> out (final layer) ==================
__global__ __launch_bounds__(256) void agg2_kernel(
    const unsigned int* __restrict__ h2u,   // [N,16] bf16-pairs
    const int2* __restrict__ csr,
    const int* __restrict__ row_start, const float* __restrict__ dinv,
    const float* __restrict__ b2, float* __restrict__ out, int N) {
    int t = blockIdx.x * 256 + threadIdx.x;
    int d = t >> 4;
    int jp = t & 15;
    if (d >= N) return;
    float di = dinv[d];
    float2 bias = ((const float2*)b2)[jp];
    unsigned int su = h2u[(size_t)d * 16 + jp];
    int beg = row_start[d], end = row_start[d + 1];
    float a0 = bf_lo(su) * di * di + bias.x;
    float a1 = bf_hi(su) * di * di + bias.y;
    int e = beg;
    for (; e + 8 <= end; e += 8) {
        int2 c[8];
#pragma unroll
        for (int k = 0; k < 8; ++k) c[k] = csr[e + k];
        unsigned int u[8];
#pragma unroll
        for (int k = 0; k < 8; ++k) u[k] = h2u[(size_t)c[k].x * 16 + jp];
#pragma unroll
        for (int k = 0; k < 8; ++k) {
            float n = __int_as_float(c[k].y);
            a0 += bf_lo(u[k]) * n; a1 += bf_hi(u[k]) * n;
        }
    }
    if (e + 4 <= end) {
        int2 c[4];
#pragma unroll
        for (int k = 0; k < 4; ++k) c[k] = csr[e + k];
        unsigned int u[4];
#pragma unroll
        for (int k = 0; k < 4; ++k) u[k] = h2u[(size_t)c[k].x * 16 + jp];
#pragma unroll
        for (int k = 0; k < 4; ++k) {
            float n = __int_as_float(c[k].y);
            a0 += bf_lo(u[k]) * n; a1 += bf_hi(u[k]) * n;
        }
        e += 4;
    }
    for (; e < end; ++e) {
        int2 c0 = csr[e];
        unsigned int u0 = h2u[(size_t)c0.x * 16 + jp];
        float n0 = __int_as_float(c0.y);
        a0 += bf_lo(u0) * n0; a1 += bf_hi(u0) * n0;
    }
    float2 r; r.x = a0; r.y = a1;
    ((float2*)(out + (size_t)d * 32))[jp] = r;
}

extern "C" void kernel_launch(void* const* d_in, const int* in_sizes, int n_in,
                              void* d_out, int out_size, void* d_ws, size_t ws_size,
                              hipStream_t stream) {
    const float* x  = (const float*)d_in[0];
    const int*   ei = (const int*)d_in[1];
    const float* W1 = (const float*)d_in[2];
    const float* b1 = (const float*)d_in[3];
    const float* W2 = (const float*)d_in[4];
    const float* b2 = (const float*)d_in[5];
    float* out = (float*)d_out;

    const int N = N_NODES;
    const int E = in_sizes[1] / 2;
    const int NBLK = (N + 1023) / 1024;     // 98 scan chunks
    const int NB = (N + 511) / 512;          // 196 buckets
    const int EB = (E + 4095) / 4096;        // 391 edge blocks

    // Workspace: csr[E]i2 | binned[E]u32 | h1b | h2b | deg | dinv |
    // row_start[N+1] | bucket_totals[256] | bucket_base[256] |
    // bucket_cursor[256] | totals[128] | offsets[128]  (~40 MB)
    char* p = (char*)d_ws;
    int2* csr = (int2*)p;                     p += (size_t)E * 8;
    unsigned int* binned = (unsigned int*)p;  p += (size_t)E * 4;
    unsigned short* h1b = (unsigned short*)p; p += (size_t)N * 64 * 2;
    unsigned short* h2b = (unsigned short*)p; p += (size_t)N * 32 * 2;
    unsigned int* deg = (unsigned int*)p;     p += (size_t)N * 4;
    float* dinv = (float*)p;                  p += (size_t)N * 4;
    int* row_start = (int*)p;                 p += (size_t)(N + 1) * 4;
    unsigned int* bucket_totals = (unsigned int*)p; p += 256 * 4;
    unsigned int* bucket_base = (unsigned int*)p;   p += 256 * 4;
    unsigned int* bucket_cursor = (unsigned int*)p; p += 256 * 4;
    unsigned int* totals = (unsigned int*)p;  p += 128 * 4;
    unsigned int* offsets = (unsigned int*)p;

    hipMemsetAsync(bucket_totals, 0, 256 * sizeof(unsigned int), stream);

    bcount_kernel<<<EB, 256, 0, stream>>>(ei + E, E, bucket_totals);
    bscan_kernel<<<1, 256, 0, stream>>>(bucket_totals, NB, E, bucket_base, bucket_cursor);
    bin_kernel<<<EB, 256, 0, stream>>>(ei, E, bucket_cursor, binned);
    degb_kernel<<<NB, 512, 0, stream>>>(binned, bucket_base, deg, dinv, N);
    scanA_kernel<<<NBLK, 256, 0, stream>>>(deg, N, totals);
    scanB_kernel<<<1, 128, 0, stream>>>(totals, NBLK, offsets, row_start, N, E);
    scanC_kernel<<<NBLK, 256, 0, stream>>>(deg, offsets, N, row_start);
    place_kernel<<<NB, 1024, 0, stream>>>(binned, row_start, dinv, csr, N);

    gemm1_kernel<<<(N + 63) / 64, 256, 0, stream>>>(x, W1, h1b, N);
    agg1_kernel<<<(N + 7) / 8, 256, 0, stream>>>((const unsigned int*)h1b, csr, row_start,
                                                 dinv, b1, W2, h2b, N);
    agg2_kernel<<<(N * 16 + 255) / 256, 256, 0, stream>>>((const unsigned int*)h2b, csr,
                                                          row_start, dinv, b2, out, N);
}

// Round 9
// 269.789 us; speedup vs baseline: 1.4392x; 1.1090x over previous
//
#include <hip/hip_runtime.h>

#define N_NODES 100000

// ---- bf16 helpers (manual, RNE) -------------------------------------------
__device__ __forceinline__ unsigned short f2bf_rn(float f) {
    unsigned int b = __float_as_uint(f);
    b += 0x7fffu + ((b >> 16) & 1u);
    return (unsigned short)(b >> 16);
}
__device__ __forceinline__ float bf_lo(unsigned int u) { return __uint_as_float(u << 16); }
__device__ __forceinline__ float bf_hi(unsigned int u) { return __uint_as_float(u & 0xffff0000u); }

// ================= bucket count: LDS hist -> few global atomics ============
__global__ __launch_bounds__(256) void bcount_kernel(const int* __restrict__ dst, int E,
                                                     unsigned int* __restrict__ bucket_totals) {
    __shared__ unsigned int cnt[256];
    int t = threadIdx.x;
    cnt[t] = 0;
    __syncthreads();
    int base = blockIdx.x * 4096;
#pragma unroll
    for (int k = 0; k < 16; ++k) {
        int e = base + k * 256 + t;
        if (e < E) {
            int d = __builtin_nontemporal_load(&dst[e]);
            atomicAdd(&cnt[(unsigned int)d >> 9], 1u);
        }
    }
    __syncthreads();
    if (cnt[t] > 0) atomicAdd(&bucket_totals[t], cnt[t]);
}

// ============ bucket scan: 196 totals -> bucket_base / bucket_cursor =======
__global__ __launch_bounds__(256) void bscan_kernel(const unsigned int* __restrict__ totals,
                                                    int nb, int E,
                                                    unsigned int* __restrict__ bucket_base,
                                                    unsigned int* __restrict__ bucket_cursor) {
    __shared__ unsigned int s[256];
    int t = threadIdx.x;
    unsigned int v = (t < nb) ? totals[t] : 0u;
    s[t] = v; __syncthreads();
    for (int off = 1; off < 256; off <<= 1) {
        unsigned int x = s[t];
        unsigned int y = (t >= off) ? s[t - off] : 0u;
        __syncthreads();
        s[t] = x + y;
        __syncthreads();
    }
    if (t < nb) {
        unsigned int excl = s[t] - v;
        bucket_base[t] = excl;
        bucket_cursor[t] = excl;
    }
    if (t == 0) bucket_base[nb] = (unsigned int)E;
}

// =================== bin: group edges by 512-node bucket ===================
// Entry: src (17b) | dst&511 (9b)<<17.
__global__ __launch_bounds__(256) void bin_kernel(const int* __restrict__ ei, int E,
                                                  unsigned int* __restrict__ bucket_cursor,
                                                  unsigned int* __restrict__ binned) {
    __shared__ unsigned int cnt[256];
    __shared__ unsigned int cur[256];
    int t = threadIdx.x;
    cnt[t] = 0;
    __syncthreads();
    int base = blockIdx.x * 4096;
    unsigned int pk[16];
    unsigned int bk[16];
#pragma unroll
    for (int k = 0; k < 16; ++k) {
        int e = base + k * 256 + t;
        if (e < E) {
            int s = __builtin_nontemporal_load(&ei[e]);
            int d = __builtin_nontemporal_load(&ei[E + e]);
            unsigned int b = (unsigned int)d >> 9;
            pk[k] = (unsigned int)s | (((unsigned int)d & 511u) << 17);
            bk[k] = b;
            atomicAdd(&cnt[b], 1u);
        } else {
            bk[k] = 0xFFFFFFFFu;
        }
    }
    __syncthreads();
    if (cnt[t] > 0) cur[t] = atomicAdd(&bucket_cursor[t], cnt[t]);
    __syncthreads();
#pragma unroll
    for (int k = 0; k < 16; ++k) {
        if (bk[k] != 0xFFFFFFFFu) {
            unsigned int pos = atomicAdd(&cur[bk[k]], 1u);
            binned[pos] = pk[k];
        }
    }
}

// ==== degb: per-bucket LDS histogram of binned -> dense deg + dinv write ===
__global__ __launch_bounds__(512) void degb_kernel(const unsigned int* __restrict__ binned,
                                                   const unsigned int* __restrict__ bucket_base,
                                                   unsigned int* __restrict__ deg,
                                                   float* __restrict__ dinv, int N) {
    __shared__ unsigned int cnt[512];
    int t = threadIdx.x;
    cnt[t] = 0;
    int beg = (int)bucket_base[blockIdx.x];
    int end = (int)bucket_base[blockIdx.x + 1];
    __syncthreads();
    for (int i = beg + t; i < end; i += 512) {
        unsigned int u = __builtin_nontemporal_load(&binned[i]);
        atomicAdd(&cnt[u >> 17], 1u);
    }
    __syncthreads();
    int node = (blockIdx.x << 9) + t;
    if (node < N) {
        unsigned int c = cnt[t];
        deg[node] = c;
        dinv[node] = rsqrtf((float)c + 1.0f);
    }
}

// ======================= row_start = exclusive scan(deg) ===================

__global__ __launch_bounds__(256) void scanA_kernel(const unsigned int* __restrict__ deg,
                                                    int n, unsigned int* __restrict__ totals) {
    __shared__ unsigned int s[256];
    int t = threadIdx.x;
    int base = blockIdx.x * 1024 + t * 4;
    unsigned int sum = 0;
#pragma unroll
    for (int k = 0; k < 4; ++k) { int i = base + k; if (i < n) sum += deg[i]; }
    s[t] = sum; __syncthreads();
    for (int off = 128; off > 0; off >>= 1) {
        if (t < off) s[t] += s[t + off];
        __syncthreads();
    }
    if (t == 0) totals[blockIdx.x] = s[0];
}

__global__ __launch_bounds__(128) void scanB_kernel(const unsigned int* __restrict__ totals,
                                                    int nblk, unsigned int* __restrict__ offsets,
                                                    int* __restrict__ row_start, int n, int E) {
    __shared__ unsigned int s[128];
    int t = threadIdx.x;
    unsigned int v = (t < nblk) ? totals[t] : 0u;
    s[t] = v; __syncthreads();
    for (int off = 1; off < 128; off <<= 1) {
        unsigned int x = s[t];
        unsigned int y = (t >= off) ? s[t - off] : 0u;
        __syncthreads();
        s[t] = x + y;
        __syncthreads();
    }
    if (t < nblk) offsets[t] = s[t] - v;
    if (t == 0) row_start[n] = E;
}

__global__ __launch_bounds__(256) void scanC_kernel(const unsigned int* __restrict__ deg,
                                                    const unsigned int* __restrict__ offsets,
                                                    int n, int* __restrict__ row_start) {
    __shared__ unsigned int s[256];
    int t = threadIdx.x;
    int base = blockIdx.x * 1024 + t * 4;
    unsigned int v[4];
    unsigned int sum = 0;
#pragma unroll
    for (int k = 0; k < 4; ++k) { int i = base + k; v[k] = (i < n) ? deg[i] : 0u; sum += v[k]; }
    s[t] = sum; __syncthreads();
    for (int off = 1; off < 256; off <<= 1) {
        unsigned int x = s[t];
        unsigned int y = (t >= off) ? s[t - off] : 0u;
        __syncthreads();
        s[t] = x + y;
        __syncthreads();
    }
    unsigned int excl = s[t] - sum + offsets[blockIdx.x];
#pragma unroll
    for (int k = 0; k < 4; ++k) {
        int i = base + k;
        if (i < n) row_start[i] = (int)excl;
        excl += v[k];
    }
}

// ====== place: one block per bucket -> row-grouped src list (4B/edge) ======
// Norms are gone (features pre-scaled by dinv), so no dinv gather here.
__global__ __launch_bounds__(1024) void place_kernel(const unsigned int* __restrict__ binned,
                                                     const int* __restrict__ row_start,
                                                     int* __restrict__ srcs, int N) {
    __shared__ int cur[512];
    int t = threadIdx.x;
    int node0 = blockIdx.x << 9;
    if (t < 512) {
        int idx = node0 + t;
        cur[t] = row_start[idx < N ? idx : N];
    }
    int endn = node0 + 512; if (endn > N) endn = N;
    int beg = row_start[node0];
    int end = row_start[endn];
    __syncthreads();
    for (int i = beg + t; i < end; i += 1024) {
        unsigned int u = __builtin_nontemporal_load(&binned[i]);
        int doff = (int)(u >> 17);
        int slot = atomicAdd(&cur[doff], 1);
        srcs[slot] = (int)(u & 0x1FFFFu);
    }
}

// ============ GEMM1: h1s[N,64](bf16) = (x @ W1) * dinv[row] ================
// 64-row tile, 256 threads, thread = 4 rows x 4 cols, all-b128 LDS reads.
__global__ __launch_bounds__(256) void gemm1_kernel(
    const float* __restrict__ x, const float* __restrict__ W,
    const float* __restrict__ dinv,
    unsigned short* __restrict__ h1b, int N) {
    __shared__ float4 Ws4[128 * 16];     // W row-major k x 64 (16 float4/row)
    __shared__ float4 xs4[64 * 33];      // 64 rows x 132 floats (pad 4)
    int tid = threadIdx.x;
    const float4* W4 = (const float4*)W;
#pragma unroll
    for (int i = 0; i < 8; ++i) Ws4[tid + 256 * i] = W4[tid + 256 * i];
    int row0 = blockIdx.x * 64;
    const float4* x4 = (const float4*)x;
#pragma unroll
    for (int i = 0; i < 8; ++i) {
        int idx = tid + 256 * i;             // 2048 float4 = 64 rows x 32
        int r = idx >> 5, c = idx & 31;
        int gr = row0 + r;
        float4 v;
        if (gr < N) v = x4[(size_t)gr * 32 + c];
        else { v.x = v.y = v.z = v.w = 0.f; }
        xs4[r * 33 + c] = v;
    }
    __syncthreads();
    int tc = tid & 15;        // col group: cols tc*4..tc*4+3
    int tr = tid >> 4;        // row group: rows tr*4..tr*4+3
    float4 acc[4];
#pragma unroll
    for (int rr = 0; rr < 4; ++rr) { acc[rr].x = 0.f; acc[rr].y = 0.f; acc[rr].z = 0.f; acc[rr].w = 0.f; }
#pragma unroll 2
    for (int k4 = 0; k4 < 32; ++k4) {
        float4 xr[4], w[4];
#pragma unroll
        for (int rr = 0; rr < 4; ++rr) xr[rr] = xs4[(tr * 4 + rr) * 33 + k4];
#pragma unroll
        for (int kk = 0; kk < 4; ++kk) w[kk] = Ws4[(k4 * 4 + kk) * 16 + tc];
#pragma unroll
        for (int rr = 0; rr < 4; ++rr) {
            acc[rr].x += xr[rr].x * w[0].x; acc[rr].y += xr[rr].x * w[0].y;
            acc[rr].z += xr[rr].x * w[0].z; acc[rr].w += xr[rr].x * w[0].w;
            acc[rr].x += xr[rr].y * w[1].x; acc[rr].y += xr[rr].y * w[1].y;
            acc[rr].z += xr[rr].y * w[1].z; acc[rr].w += xr[rr].y * w[1].w;
            acc[rr].x += xr[rr].z * w[2].x; acc[rr].y += xr[rr].z * w[2].y;
            acc[rr].z += xr[rr].z * w[2].z; acc[rr].w += xr[rr].z * w[2].w;
            acc[rr].x += xr[rr].w * w[3].x; acc[rr].y += xr[rr].w * w[3].y;
            acc[rr].z += xr[rr].w * w[3].z; acc[rr].w += xr[rr].w * w[3].w;
        }
    }
#pragma unroll
    for (int rr = 0; rr < 4; ++rr) {
        int r = row0 + tr * 4 + rr;
        if (r < N) {
            float di = dinv[r];
            ushort4 o;
            o.x = f2bf_rn(acc[rr].x * di); o.y = f2bf_rn(acc[rr].y * di);
            o.z = f2bf_rn(acc[rr].z * di); o.w = f2bf_rn(acc[rr].w * di);
            *(ushort4*)(h1b + (size_t)r * 64 + tc * 4) = o;   // 8B coalesced
        }
    }
}

// ============ Aggregation 1 (+bias+relu) fused with GEMM2 ==================
// h = relu(dinv[d] * (sum_e h1s[src] + h1s[d]) + b1); h2s = (h @ W2)*dinv[d].
// 32 lanes/node, 8 nodes/block, batch-16/8/4 deep prefetch (no per-edge norm).
__global__ __launch_bounds__(256) void agg1_kernel(
    const unsigned int* __restrict__ h1u,   // [N,32] bf16-pairs (pre-scaled)
    const int* __restrict__ srcs,
    const int* __restrict__ row_start, const float* __restrict__ dinv,
    const float* __restrict__ b1, const float* __restrict__ W2,
    unsigned short* __restrict__ h2b, int N) {
    __shared__ float W2s[64 * 32];
    __shared__ float hr[8][64];
    int tid = threadIdx.x;
    const float4* W24 = (const float4*)W2;
    float4* W2s4 = (float4*)W2s;
#pragma unroll
    for (int i = 0; i < 2; ++i) W2s4[tid + 256 * i] = W24[tid + 256 * i];
    __syncthreads();
    int nib = tid >> 5;           // node-in-block 0..7
    int jp = tid & 31;            // feature pair
    int d = blockIdx.x * 8 + nib;
    if (d >= N) return;           // no barriers after this point
    float di = dinv[d];
    float2 bias = ((const float2*)b1)[jp];
    unsigned int su = h1u[(size_t)d * 32 + jp];
    int beg = row_start[d], end = row_start[d + 1];
    float a0 = bf_lo(su);         // self-loop term (pre-scaled)
    float a1 = bf_hi(su);
    int e = beg;
    for (; e + 16 <= end; e += 16) {   // batch-16: 16 gathers in flight
        int c[16];
#pragma unroll
        for (int k = 0; k < 16; ++k) c[k] = srcs[e + k];
        unsigned int u[16];
#pragma unroll
        for (int k = 0; k < 16; ++k) u[k] = h1u[(size_t)c[k] * 32 + jp];
#pragma unroll
        for (int k = 0; k < 16; ++k) { a0 += bf_lo(u[k]); a1 += bf_hi(u[k]); }
    }
    if (e + 8 <= end) {
        int c[8];
#pragma unroll
        for (int k = 0; k < 8; ++k) c[k] = srcs[e + k];
        unsigned int u[8];
#pragma unroll
        for (int k = 0; k < 8; ++k) u[k] = h1u[(size_t)c[k] * 32 + jp];
#pragma unroll
        for (int k = 0; k < 8; ++k) { a0 += bf_lo(u[k]); a1 += bf_hi(u[k]); }
        e += 8;
    }
    if (e + 4 <= end) {
        int c[4];
#pragma unroll
        for (int k = 0; k < 4; ++k) c[k] = srcs[e + k];
        unsigned int u[4];
#pragma unroll
        for (int k = 0; k < 4; ++k) u[k] = h1u[(size_t)c[k] * 32 + jp];
#pragma unroll
        for (int k = 0; k < 4; ++k) { a0 += bf_lo(u[k]); a1 += bf_hi(u[k]); }
        e += 4;
    }
    for (; e < end; ++e) {
        unsigned int u0 = h1u[(size_t)srcs[e] * 32 + jp];
        a0 += bf_lo(u0); a1 += bf_hi(u0);
    }
    float h0 = fmaxf(a0 * di + bias.x, 0.f);
    float h1v = fmaxf(a1 * di + bias.y, 0.f);
    hr[nib][2 * jp] = h0;             // intra-wave LDS RAW, lgkmcnt-ordered
    hr[nib][2 * jp + 1] = h1v;
    const float* hrw = hr[nib];
    float p = 0.f;
#pragma unroll 8
    for (int k = 0; k < 64; ++k)
        p += hrw[k] * W2s[k * 32 + jp];
    h2b[(size_t)d * 32 + jp] = f2bf_rn(p * di);   // pre-scale for layer 2
}

// ===================== Aggregation 2 -> out (final layer) ==================
// out = dinv[d] * (sum_e h2s[src] + h2s[d]) + b2.  16 lanes/node.
__global__ __launch_bounds__(256) void agg2_kernel(
    const unsigned int* __restrict__ h2u,   // [N,16] bf16-pairs (pre-scaled)
    const int* __restrict__ srcs,
    const int* __restrict__ row_start, const float* __restrict__ dinv,
    const float* __restrict__ b2, float* __restrict__ out, int N) {
    int t = blockIdx.x * 256 + threadIdx.x;
    int d = t >> 4;
    int jp = t & 15;
    if (d >= N) return;
    float di = dinv[d];
    float2 bias = ((const float2*)b2)[jp];
    unsigned int su = h2u[(size_t)d * 16 + jp];
    int beg = row_start[d], end = row_start[d + 1];
    float a0 = bf_lo(su);
    float a1 = bf_hi(su);
    int e = beg;
    for (; e + 16 <= end; e += 16) {
        int c[16];
#pragma unroll
        for (int k = 0; k < 16; ++k) c[k] = srcs[e + k];
        unsigned int u[16];
#pragma unroll
        for (int k = 0; k < 16; ++k) u[k] = h2u[(size_t)c[k] * 16 + jp];
#pragma unroll
        for (int k = 0; k < 16; ++k) { a0 += bf_lo(u[k]); a1 += bf_hi(u[k]); }
    }
    if (e + 8 <= end) {
        int c[8];
#pragma unroll
        for (int k = 0; k < 8; ++k) c[k] = srcs[e + k];
        unsigned int u[8];
#pragma unroll
        for (int k = 0; k < 8; ++k) u[k] = h2u[(size_t)c[k] * 16 + jp];
#pragma unroll
        for (int k = 0; k < 8; ++k) { a0 += bf_lo(u[k]); a1 += bf_hi(u[k]); }
        e += 8;
    }
    if (e + 4 <= end) {
        int c[4];
#pragma unroll
        for (int k = 0; k < 4; ++k) c[k] = srcs[e + k];
        unsigned int u[4];
#pragma unroll
        for (int k = 0; k < 4; ++k) u[k] = h2u[(size_t)c[k] * 16 + jp];
#pragma unroll
        for (int k = 0; k < 4; ++k) { a0 += bf_lo(u[k]); a1 += bf_hi(u[k]); }
        e += 4;
    }
    for (; e < end; ++e) {
        unsigned int u0 = h2u[(size_t)srcs[e] * 16 + jp];
        a0 += bf_lo(u0); a1 += bf_hi(u0);
    }
    float2 r;
    r.x = a0 * di + bias.x;
    r.y = a1 * di + bias.y;
    ((float2*)(out + (size_t)d * 32))[jp] = r;
}

extern "C" void kernel_launch(void* const* d_in, const int* in_sizes, int n_in,
                              void* d_out, int out_size, void* d_ws, size_t ws_size,
                              hipStream_t stream) {
    const float* x  = (const float*)d_in[0];
    const int*   ei = (const int*)d_in[1];
    const float* W1 = (const float*)d_in[2];
    const float* b1 = (const float*)d_in[3];
    const float* W2 = (const float*)d_in[4];
    const float* b2 = (const float*)d_in[5];
    float* out = (float*)d_out;

    const int N = N_NODES;
    const int E = in_sizes[1] / 2;
    const int NBLK = (N + 1023) / 1024;     // 98 scan chunks
    const int NB = (N + 511) / 512;          // 196 buckets
    const int EB = (E + 4095) / 4096;        // 391 edge blocks

    // Workspace: srcs[E]i32 | binned[E]u32 | h1b | h2b | deg | dinv |
    // row_start[N+1] | bucket_totals[256] | bucket_base[256] |
    // bucket_cursor[256] | totals[128] | offsets[128]  (~33 MB)
    char* p = (char*)d_ws;
    int* srcs = (int*)p;                      p += (size_t)E * 4;
    unsigned int* binned = (unsigned int*)p;  p += (size_t)E * 4;
    unsigned short* h1b = (unsigned short*)p; p += (size_t)N * 64 * 2;
    unsigned short* h2b = (unsigned short*)p; p += (size_t)N * 32 * 2;
    unsigned int* deg = (unsigned int*)p;     p += (size_t)N * 4;
    float* dinv = (float*)p;                  p += (size_t)N * 4;
    int* row_start = (int*)p;                 p += (size_t)(N + 1) * 4;
    unsigned int* bucket_totals = (unsigned int*)p; p += 256 * 4;
    unsigned int* bucket_base = (unsigned int*)p;   p += 256 * 4;
    unsigned int* bucket_cursor = (unsigned int*)p; p += 256 * 4;
    unsigned int* totals = (unsigned int*)p;  p += 128 * 4;
    unsigned int* offsets = (unsigned int*)p;

    hipMemsetAsync(bucket_totals, 0, 256 * sizeof(unsigned int), stream);

    bcount_kernel<<<EB, 256, 0, stream>>>(ei + E, E, bucket_totals);
    bscan_kernel<<<1, 256, 0, stream>>>(bucket_totals, NB, E, bucket_base, bucket_cursor);
    bin_kernel<<<EB, 256, 0, stream>>>(ei, E, bucket_cursor, binned);
    degb_kernel<<<NB, 512, 0, stream>>>(binned, bucket_base, deg, dinv, N);
    scanA_kernel<<<NBLK, 256, 0, stream>>>(deg, N, totals);
    scanB_kernel<<<1, 128, 0, stream>>>(totals, NBLK, offsets, row_start, N, E);
    scanC_kernel<<<NBLK, 256, 0, stream>>>(deg, offsets, N, row_start);
    place_kernel<<<NB, 1024, 0, stream>>>(binned, row_start, srcs, N);

    gemm1_kernel<<<(N + 63) / 64, 256, 0, stream>>>(x, W1, dinv, h1b, N);
    agg1_kernel<<<(N + 7) / 8, 256, 0, stream>>>((const unsigned int*)h1b, srcs, row_start,
                                                 dinv, b1, W2, h2b, N);
    agg2_kernel<<<(N * 16 + 255) / 256, 256, 0, stream>>>((const unsigned int*)h2b, srcs,
                                                          row_start, dinv, b2, out, N);
}